// Round 9
// baseline (38194.879 us; speedup 1.0000x reference)
//
#include <hip/hip_runtime.h>

#define SEQ   2048
#define HID   512
#define NB    32
#define NWG   256
#define NTHR  256
#define POLL_CAP 5000000
#define REP_STRIDE (163840 / 4)   // u32 stride between replica areas (160 KB)

typedef __attribute__((ext_vector_type(8))) short bf16x8;
typedef __attribute__((ext_vector_type(4))) float f32x4;
typedef __attribute__((ext_vector_type(4))) unsigned u32x4;
typedef __attribute__((ext_vector_type(2))) unsigned u32x2;

__device__ __forceinline__ float sigf(float x) { return 1.0f / (1.0f + __expf(-x)); }
__device__ __forceinline__ float tanhf_fast(float x) {
    float e = __expf(2.0f * x);
    return (e - 1.0f) / (e + 1.0f);
}
__device__ __forceinline__ short f2bf(float f) {
    unsigned u = __float_as_uint(f);
    unsigned r = (u + 0x7FFFu + ((u >> 16) & 1u)) >> 16;
    return (short)r;
}
__device__ __forceinline__ float bf2f(unsigned short s) {
    return __uint_as_float(((unsigned)s) << 16);
}
__device__ __forceinline__ unsigned pack2(float a, float b) {
    return (unsigned)(unsigned short)f2bf(a) | ((unsigned)(unsigned short)f2bf(b) << 16);
}
__device__ __forceinline__ bf16x8 cvt8(float4 a, float4 b) {
    bf16x8 r;
    r[0] = f2bf(a.x); r[1] = f2bf(a.y); r[2] = f2bf(a.z); r[3] = f2bf(a.w);
    r[4] = f2bf(b.x); r[5] = f2bf(b.y); r[6] = f2bf(b.z); r[7] = f2bf(b.w);
    return r;
}

// PROVEN primitives (rounds 2-6, absmax 0.0): relaxed agent-scope atomics,
// prompt cross-WG visibility, no fence, no L1/L2 maintenance storms.
__device__ __forceinline__ unsigned ld_a(const unsigned* p) {
    return __hip_atomic_load((unsigned*)p, __ATOMIC_RELAXED, __HIP_MEMORY_SCOPE_AGENT);
}
__device__ __forceinline__ void st_a(unsigned* p, unsigned v) {
    __hip_atomic_store(p, v, __ATOMIC_RELAXED, __HIP_MEMORY_SCOPE_AGENT);
}

// XCD-replicated persistent LSTM (R7 structure, R4-proven memory ops).
// 8 replicas (physical XCD via s_getreg HW_REG_XCC_ID), 32 WGs each, every
// replica computes the FULL 2-layer recurrence redundantly. Barriers span
// only the replica's 32 WGs (dense 32-u32 flag block per replica).
// Per WG: 32 hidden cols x 4 gates = 128 gate rows; bf16 weights resident in
// registers (A[2][2][16], 256 regs); 4 waves; MFMA 16x16x32 (proven layout).
__global__ __launch_bounds__(NTHR, 1) void lstm_xcd(
    const int*   __restrict__ tokens, const float* __restrict__ emb,
    const float* __restrict__ w_ih,   const float* __restrict__ w_hh,
    const float* __restrict__ b_ih,   const float* __restrict__ b_hh,
    const float* __restrict__ fc_w,   const float* __restrict__ fc_b,
    float* __restrict__ out, unsigned* __restrict__ ws)
{
    __shared__ __attribute__((aligned(16))) short inp[2][NB][520];  // double-buffered input
    __shared__ __attribute__((aligned(16))) float gbuf[4][NB][36];
    __shared__ int sh_xcc, sh_rank;

    const int tid = threadIdx.x;

    // ---- registration: physical XCD id + per-XCD rank ----
    if (tid == 0) {
        unsigned xr;
        asm volatile("s_getreg_b32 %0, hwreg(HW_REG_XCC_ID)" : "=s"(xr));
        xr &= 7u;
        sh_xcc = (int)xr;
        sh_rank = (int)__hip_atomic_fetch_add(ws + 16 + xr, 1u,
                      __ATOMIC_ACQ_REL, __HIP_MEMORY_SCOPE_AGENT);
    }
    __syncthreads();
    const int xcc = sh_xcc, lrank = sh_rank;

    // ---- one-time global barrier (runs once; cost irrelevant) ----
    if (tid == 0) {
        __hip_atomic_fetch_add(ws, 1u, __ATOMIC_ACQ_REL, __HIP_MEMORY_SCOPE_AGENT);
        int pp = 0;
        while (__hip_atomic_load(ws, __ATOMIC_ACQUIRE, __HIP_MEMORY_SCOPE_AGENT) < NWG) {
            __builtin_amdgcn_s_sleep(8);
            if (++pp > POLL_CAP) break;
        }
    }
    __syncthreads();
    const unsigned mycnt = __hip_atomic_load(ws + 16 + xcc, __ATOMIC_ACQUIRE,
                                             __HIP_MEMORY_SCOPE_AGENT);
    if (mycnt < 32u || lrank >= 32) return;   // replica didn't form / spare WG

    // ---- replica workspace ----
    unsigned* const repbase = ws + 1024 + (size_t)xcc * REP_STRIDE;
    unsigned* const flags = repbase;               // 32 dense u32 (2 lines)
    unsigned* const h0a_  = repbase + 1024;        // each h buf: u32[32][256] = 32 KB
    unsigned* const h0b_  = h0a_ + 8192;
    unsigned* const h1a_  = h0a_ + 16384;
    unsigned* const h1b_  = h0a_ + 24576;

    const int layer = lrank >> 4;          // 0..1
    const int c0    = (lrank & 15) * 32;   // WG's 32 hidden cols
    const int wv    = tid >> 6;
    const int lane  = tid & 63;
    const int i16   = lane & 15;
    const int hi    = lane >> 4;

    // ---- resident weights: A[part(ih/hh)][m-tile][k-tile] ----
    bf16x8 A[2][2][16];
    #pragma unroll
    for (int m = 0; m < 2; ++m) {
        const int g   = 2 * m + (i16 >> 3);
        const int row = g * 512 + c0 + wv * 8 + (i16 & 7);
        const float* pih = w_ih + ((size_t)layer * 2048 + row) * 512;
        const float* phh = w_hh + ((size_t)layer * 2048 + row) * 512;
        #pragma unroll
        for (int kt = 0; kt < 16; ++kt) {
            const int k = kt * 32 + hi * 8;
            A[0][m][kt] = cvt8(*(const float4*)(pih + k), *(const float4*)(pih + k + 4));
            A[1][m][kt] = cvt8(*(const float4*)(phh + k), *(const float4*)(phh + k + 4));
        }
    }

    // ---- cell-updater role: thread -> (batch bt, col-quad jp) ----
    const int bt = tid & 31, jp = tid >> 5;
    float biasr[4][4];
    #pragma unroll
    for (int g = 0; g < 4; ++g)
        #pragma unroll
        for (int i = 0; i < 4; ++i) {
            const int c = c0 + jp * 4 + i;
            biasr[g][i] = b_ih[layer * 2048 + g * 512 + c]
                        + b_hh[layer * 2048 + g * 512 + c];
        }
    float cst[4] = {0.f, 0.f, 0.f, 0.f};
    f32x4 acc[2][2];

    short* const inpB = &inp[0][0][0];

    // stage 512-wide h vector (u32-packed) into LDS buffer sel, via atomic loads
    auto stage_h = [&](const unsigned* hsrc, int sel) {
        const int b  = tid >> 3;
        const int j0 = (tid & 7) * 32;
        const unsigned* src = hsrc + b * 256 + j0;
        unsigned q[32];
        #pragma unroll
        for (int i = 0; i < 32; ++i) q[i] = ld_a(src + i);
        char* dst = (char*)inpB + sel * 33280 + b * 1040 + j0 * 4;
        #pragma unroll
        for (int i = 0; i < 8; ++i) {
            u32x4 v = {q[4 * i], q[4 * i + 1], q[4 * i + 2], q[4 * i + 3]};
            *(u32x4*)(dst + i * 16) = v;
        }
    };

    // stage x(tt) = embedding rows, f32 -> bf16, into buffer 0 (plain cached loads)
    auto stage_x = [&](int tt) {
        const int b  = tid >> 3;
        const int k0 = (tid & 7) * 64;
        const float* xr = emb + (size_t)tokens[b * SEQ + tt] * 512 + k0;
        char* dst = (char*)inpB + b * 1040 + k0 * 2;
        #pragma unroll
        for (int i = 0; i < 8; ++i) {
            float4 a = *(const float4*)(xr + i * 8);
            float4 c = *(const float4*)(xr + i * 8 + 4);
            *(bf16x8*)(dst + i * 16) = cvt8(a, c);
        }
    };

#define ZERO_ACC() do { acc[0][0] = f32x4{0.f,0.f,0.f,0.f}; acc[0][1] = f32x4{0.f,0.f,0.f,0.f}; \
                        acc[1][0] = f32x4{0.f,0.f,0.f,0.f}; acc[1][1] = f32x4{0.f,0.f,0.f,0.f}; } while (0)

#define DO_MFMA(P, SEL) do { \
    _Pragma("unroll") \
    for (int kt = 0; kt < 16; ++kt) { \
        const char* pb = (const char*)inpB + (SEL) * 33280 + i16 * 1040 + kt * 64 + hi * 16; \
        bf16x8 B0 = *(const bf16x8*)pb; \
        bf16x8 B1 = *(const bf16x8*)(pb + 16 * 1040); \
        acc[0][0] = __builtin_amdgcn_mfma_f32_16x16x32_bf16(A[P][0][kt], B0, acc[0][0], 0, 0, 0); \
        acc[1][0] = __builtin_amdgcn_mfma_f32_16x16x32_bf16(A[P][1][kt], B0, acc[1][0], 0, 0, 0); \
        acc[0][1] = __builtin_amdgcn_mfma_f32_16x16x32_bf16(A[P][0][kt], B1, acc[0][1], 0, 0, 0); \
        acc[1][1] = __builtin_amdgcn_mfma_f32_16x16x32_bf16(A[P][1][kt], B1, acc[1][1], 0, 0, 0); \
    } } while (0)

    auto write_gbuf = [&]() {
        #pragma unroll
        for (int m = 0; m < 2; ++m)
            #pragma unroll
            for (int nt = 0; nt < 2; ++nt)
                *(f32x4*)&gbuf[2 * m + (hi >> 1)][nt * 16 + i16][wv * 8 + (hi & 1) * 4] = acc[m][nt];
    };

    auto cell_store = [&](unsigned* hout) {
        f32x4 gi = *(f32x4*)&gbuf[0][bt][jp * 4];
        f32x4 gf = *(f32x4*)&gbuf[1][bt][jp * 4];
        f32x4 gg = *(f32x4*)&gbuf[2][bt][jp * 4];
        f32x4 go = *(f32x4*)&gbuf[3][bt][jp * 4];
        float hv[4];
        #pragma unroll
        for (int i = 0; i < 4; ++i) {
            cst[i] = sigf(gf[i] + biasr[1][i]) * cst[i]
                   + sigf(gi[i] + biasr[0][i]) * tanhf_fast(gg[i] + biasr[2][i]);
            hv[i]  = sigf(go[i] + biasr[3][i]) * tanhf_fast(cst[i]);
        }
        unsigned* hp = hout + bt * 256 + (c0 >> 1) + jp * 2;
        st_a(hp + 0, pack2(hv[0], hv[1]));
        st_a(hp + 1, pack2(hv[2], hv[3]));
    };

    bool broken = false;
    int polls = 0;

    auto post_flag = [&](unsigned val) {
        if (tid == 0) st_a(flags + lrank, val);
    };
    // single-hop sweep: lanes 0-31 of wave 0 each watch one dense flag (2 lines)
    auto poll_flags = [&](unsigned target) {
        if (wv == 0) {
            for (;;) {
                bool mine = true;
                if (!broken && lane < 32) mine = (ld_a(flags + lane) >= target);
                if (broken || __all(mine)) break;
                __builtin_amdgcn_s_sleep(2);
                if (++polls > POLL_CAP) broken = true;   // bailout: never hang
            }
        }
    };

    // ---- prologue: L0's x(0)-part before the loop ----
    ZERO_ACC();
    if (layer == 0) { stage_x(0); __syncthreads(); DO_MFMA(0, 0); }

    for (int k = 0; k <= SEQ; ++k) {
        const int t = layer ? (k - 1) : k;
        const bool active = (t >= 0 && t < SEQ);
        if (active) {
            const int p = t & 1;
            if (layer == 0) {
                stage_h(p ? h0a_ : h0b_, 1);          // h0[t-1] -> buf1
                __syncthreads();
                DO_MFMA(1, 1);                         // hh-part onto resident x-part acc
                write_gbuf();
                __syncthreads();
                cell_store(p ? h0b_ : h0a_);           // h0[t]
                asm volatile("s_waitcnt vmcnt(0)" ::: "memory");  // per-wave drain
                if (t + 1 < SEQ) stage_x(t + 1);       // prefetch next x -> buf0
                __syncthreads();                       // all waves' h stores done
                post_flag((unsigned)(k + 1));
                if (t + 1 < SEQ) { ZERO_ACC(); DO_MFMA(0, 0); }  // x-part under the wait
                poll_flags((unsigned)(k + 1));
                __syncthreads();
            } else {
                stage_h(p ? h0b_ : h0a_, 0);           // h0[t]   -> buf0
                stage_h(p ? h1a_ : h1b_, 1);           // h1[t-1] -> buf1 (loads overlap)
                __syncthreads();
                ZERO_ACC();
                DO_MFMA(0, 0);                         // W_ih1 . h0[t]
                DO_MFMA(1, 1);                         // W_hh1 . h1[t-1]
                write_gbuf();
                __syncthreads();
                cell_store(p ? h1b_ : h1a_);           // h1[t]
                asm volatile("s_waitcnt vmcnt(0)" ::: "memory");
                __syncthreads();
                post_flag((unsigned)(k + 1));
                poll_flags((unsigned)(k + 1));
                __syncthreads();
            }
        } else {
            post_flag((unsigned)(k + 1));
            poll_flags((unsigned)(k + 1));
            __syncthreads();
        }
    }

    // ---- FC head: rank-0 WG of each formed replica (identical outputs) ----
    if (lrank == 0 && tid < 64) {
        const int b = tid >> 1, o = tid & 1;
        float accf = 0.f;
        for (int j2 = 0; j2 < 256; ++j2) {
            unsigned u = ld_a(h1b_ + b * 256 + j2);    // t=2047 parity 1 -> h1b
            accf += bf2f((unsigned short)(u & 0xFFFFu)) * fc_w[o * HID + 2 * j2]
                  + bf2f((unsigned short)(u >> 16))     * fc_w[o * HID + 2 * j2 + 1];
        }
        out[b * 2 + o] = sigf(accf + fc_b[o]);
    }
}

extern "C" void kernel_launch(void* const* d_in, const int* in_sizes, int n_in,
                              void* d_out, int out_size, void* d_ws, size_t ws_size,
                              hipStream_t stream)
{
    const int*   tokens = (const int*)d_in[0];
    const float* emb    = (const float*)d_in[1];
    const float* w_ih   = (const float*)d_in[2];
    const float* w_hh   = (const float*)d_in[3];
    const float* b_ih   = (const float*)d_in[4];
    const float* b_hh   = (const float*)d_in[5];
    const float* fc_w   = (const float*)d_in[6];
    const float* fc_b   = (const float*)d_in[7];

    unsigned* ws = (unsigned*)d_ws;
    // layout: [0] gbar | [16..23] per-XCD rank counters | +4096B: 8 replica areas
    // (160 KB stride: 32 flags @+0, four 32KB h buffers @+4KB)
    hipMemsetAsync(d_ws, 0, 4096 + (size_t)8 * 163840, stream);

    lstm_xcd<<<dim3(NWG), dim3(NTHR), 0, stream>>>(
        tokens, emb, w_ih, w_hh, b_ih, b_hh, fc_w, fc_b,
        (float*)d_out, ws);
}

// Round 10
// 22914.204 us; speedup vs baseline: 1.6669x; 1.6669x over previous
//
#include <hip/hip_runtime.h>

#define SEQ   2048
#define EMBD  512
#define HID   512
#define NB    32
#define NSL   128   // WGs per layer
#define NWGW  256   // worker WGs
#define NTHR  256
#define POLL_CAP 5000000

typedef __attribute__((ext_vector_type(8))) short bf16x8;
typedef __attribute__((ext_vector_type(4))) float f32x4;

__device__ __forceinline__ float sigf(float x) { return 1.0f / (1.0f + __expf(-x)); }
__device__ __forceinline__ float tanhf_fast(float x) {
    float e = __expf(2.0f * x);
    return (e - 1.0f) / (e + 1.0f);
}
__device__ __forceinline__ short f2bf(float f) {
    unsigned u = __float_as_uint(f);
    unsigned r = (u + 0x7FFFu + ((u >> 16) & 1u)) >> 16;
    return (short)r;
}
__device__ __forceinline__ float bf2f(unsigned short s) {
    return __uint_as_float(((unsigned)s) << 16);
}
__device__ __forceinline__ bf16x8 cvt8(float4 a, float4 b) {
    bf16x8 r;
    r[0] = f2bf(a.x); r[1] = f2bf(a.y); r[2] = f2bf(a.z); r[3] = f2bf(a.w);
    r[4] = f2bf(b.x); r[5] = f2bf(b.y); r[6] = f2bf(b.z); r[7] = f2bf(b.w);
    return r;
}

// Relaxed agent-scope atomics: proven prompt LLC visibility (rounds 2-6, 9).
__device__ __forceinline__ unsigned ld_a(const unsigned* p) {
    return __hip_atomic_load((unsigned*)p, __ATOMIC_RELAXED, __HIP_MEMORY_SCOPE_AGENT);
}
__device__ __forceinline__ void st_a(unsigned* p, unsigned v) {
    __hip_atomic_store(p, v, __ATOMIC_RELAXED, __HIP_MEMORY_SCOPE_AGENT);
}
__device__ __forceinline__ bf16x8 ld_h8(const unsigned* p) {
    union { unsigned u[4]; bf16x8 v; } x;
    x.u[0] = ld_a(p + 0); x.u[1] = ld_a(p + 1);
    x.u[2] = ld_a(p + 2); x.u[3] = ld_a(p + 3);
    return x.v;
}

// MFMA half-GEMM on h-state (u32-packed bf16 pairs, direct from LLC) -> LDS partials
__device__ __forceinline__ void h_mfma(
    const unsigned* __restrict__ bsrc, const bf16x8* A,
    int kb, int hi, int i16, int w, float (*part)[16][16])
{
    f32x4 acc0 = {0.f, 0.f, 0.f, 0.f};
    f32x4 acc1 = {0.f, 0.f, 0.f, 0.f};
    const unsigned* pb0 = bsrc + (size_t)i16 * (HID / 2);
    const unsigned* pb1 = bsrc + (size_t)(16 + i16) * (HID / 2);
    const int kb2 = kb / 2;
    #pragma unroll
    for (int q = 0; q < 8; ++q) {
        int ko2 = kb2 + q * 16 + hi * 4;
        bf16x8 B0 = ld_h8(pb0 + ko2);
        bf16x8 B1 = ld_h8(pb1 + ko2);
        acc0 = __builtin_amdgcn_mfma_f32_16x16x32_bf16(A[q], B0, acc0, 0, 0, 0);
        acc1 = __builtin_amdgcn_mfma_f32_16x16x32_bf16(A[q], B1, acc1, 0, 0, 0);
    }
    #pragma unroll
    for (int r = 0; r < 4; ++r) {
        part[w * 2 + 0][hi * 4 + r][i16] = acc0[r];
        part[w * 2 + 1][hi * 4 + r][i16] = acc1[r];
    }
}

// Layer-0 x-half (embedding gather) for step tt -> LDS partials (under the wait)
__device__ __forceinline__ void l0_x_mfma(
    int tt, const int* __restrict__ tokens, const float* __restrict__ emb,
    const bf16x8* A, int kb, int hi, int i16, int w, float (*part)[16][16])
{
    f32x4 acc0 = {0.f, 0.f, 0.f, 0.f};
    f32x4 acc1 = {0.f, 0.f, 0.f, 0.f};
    const int b0 = i16, b1 = 16 + i16;
    const size_t r0 = (size_t)tokens[b0 * SEQ + tt] * EMBD;
    const size_t r1 = (size_t)tokens[b1 * SEQ + tt] * EMBD;
    #pragma unroll
    for (int q = 0; q < 8; ++q) {
        int koff = kb + q * 32 + hi * 8;
        float4 xa0 = *(const float4*)(emb + r0 + koff);
        float4 xb0 = *(const float4*)(emb + r0 + koff + 4);
        float4 xa1 = *(const float4*)(emb + r1 + koff);
        float4 xb1 = *(const float4*)(emb + r1 + koff + 4);
        bf16x8 B0 = cvt8(xa0, xb0);
        bf16x8 B1 = cvt8(xa1, xb1);
        acc0 = __builtin_amdgcn_mfma_f32_16x16x32_bf16(A[q], B0, acc0, 0, 0, 0);
        acc1 = __builtin_amdgcn_mfma_f32_16x16x32_bf16(A[q], B1, acc1, 0, 0, 0);
    }
    #pragma unroll
    for (int r = 0; r < 4; ++r) {
        part[w * 2 + 0][hi * 4 + r][i16] = acc0[r];
        part[w * 2 + 1][hi * 4 + r][i16] = acc1[r];
    }
}

// Persistent kernel, 256 worker WGs + 1 dedicated barrier-master WG.
// Phase: [MFMA on confirmed inputs] SYNC [gates + h store + vmcnt + dense slot
// store] SYNC [L0 waves 0-1: next-step x-half | tid 255: poll my epoch copy]
// SYNC. Master (WG 256): sweep 256 dense slots (16 lines, sole reader),
// publish 8 epoch copies on 8 separate lines (<=32 pollers each).
__global__ __launch_bounds__(NTHR, 1) void lstm_persist(
    const int*   __restrict__ tokens, const float* __restrict__ emb,
    const float* __restrict__ w_ih,   const float* __restrict__ w_hh,
    const float* __restrict__ b_ih,   const float* __restrict__ b_hh,
    const float* __restrict__ fc_w,   const float* __restrict__ fc_b,
    float* __restrict__ out,
    unsigned* __restrict__ slots, unsigned* __restrict__ epochs,
    unsigned* __restrict__ hbuf)
{
    const int tid = threadIdx.x;
    const int wg  = blockIdx.x;

    // ================= dedicated barrier master =================
    if (wg == NWGW) {
        if (tid < 64) {
            bool mbroken = false; int mpolls = 0;
            for (int k = 0; k <= SEQ && !mbroken; ++k) {
                const unsigned target = (unsigned)(k + 1);
                for (;;) {
                    unsigned v0 = ld_a(&slots[tid +   0]);
                    unsigned v1 = ld_a(&slots[tid +  64]);
                    unsigned v2 = ld_a(&slots[tid + 128]);
                    unsigned v3 = ld_a(&slots[tid + 192]);
                    bool ok = (v0 >= target) & (v1 >= target) & (v2 >= target) & (v3 >= target);
                    if (__all(ok)) break;
                    if (++mpolls > POLL_CAP) { mbroken = true; break; }
                }
                if (!mbroken && tid < 8) st_a(&epochs[tid * 32], target);
            }
            // bailout: release workers so nobody hangs (answer may be wrong)
            if (mbroken && tid < 8) st_a(&epochs[tid * 32], (unsigned)(SEQ + 1));
        }
        return;
    }

    // ================= worker WGs =================
    __shared__ float part[8][16][16];   // [w*2+ct][m][c]

    const bool l1   = (wg >= NSL);
    const int s     = l1 ? (wg - NSL) : wg;
    const int layer = l1 ? 1 : 0;
    const int w     = tid >> 6;       // wave 0..3
    const int lane  = tid & 63;
    const int i16   = lane & 15;
    const int hi    = lane >> 4;
    const int kb    = (w & 1) * 256;
    const bool xw   = (w < 2);

    unsigned* const h0a_ = hbuf;
    unsigned* const h0b_ = hbuf + NB * HID / 2;
    unsigned* const h1a_ = hbuf + 2 * NB * HID / 2;
    unsigned* const h1b_ = hbuf + 3 * NB * HID / 2;

    // ---- A fragments (weights) resident in registers for the whole run ----
    const int m    = i16;
    const int gg_  = m >> 2, jj_ = m & 3;
    const int rowg = gg_ * 512 + s * 4 + jj_;
    const float* wbase = xw ? (w_ih + ((size_t)layer * 2048 + rowg) * 512)
                            : (w_hh + ((size_t)layer * 2048 + rowg) * 512);
    bf16x8 A[8];
    #pragma unroll
    for (int q = 0; q < 8; ++q) {
        int koff = kb + q * 32 + hi * 8;
        float4 wa = *(const float4*)(wbase + koff);
        float4 wb = *(const float4*)(wbase + koff + 4);
        A[q] = cvt8(wa, wb);
    }

    // ---- per-thread cell state: threads 0..63 own (pr, eb), 2 hidden cols ----
    const int eb  = tid & 31;
    const int pr  = tid >> 5;          // valid for tid<64
    const int ect = eb >> 4, ec = eb & 15;
    float cA = 0.0f, cB = 0.0f;
    float biasA[4] = {0.f,0.f,0.f,0.f}, biasB[4] = {0.f,0.f,0.f,0.f};
    if (tid < 64) {
        #pragma unroll
        for (int g = 0; g < 4; ++g) {
            int rg = g * 512 + s * 4 + pr * 2;
            biasA[g] = b_ih[layer * 2048 + rg]     + b_hh[layer * 2048 + rg];
            biasB[g] = b_ih[layer * 2048 + rg + 1] + b_hh[layer * 2048 + rg + 1];
        }
    }

    unsigned* const myepoch = epochs + (wg & 7) * 32;
    bool broken = false;
    int polls = 0;

    // ---- prologue: L0 x-half for t=0 (part slots 0..3) ----
    if (!l1 && xw) l0_x_mfma(0, tokens, emb, A, kb, hi, i16, w, part);

    for (int k = 0; k <= SEQ; ++k) {
        const int t = l1 ? (k - 1) : k;
        const bool active = (t >= 0 && t < SEQ);
        const int p = t & 1;

        // ---- step 1: MFMA halves whose inputs were confirmed last phase ----
        if (active) {
            if (!l1) {
                if (!xw) {
                    const unsigned* h0pp = p ? h0a_ : h0b_;   // h0[t-1]
                    h_mfma(h0pp, A, kb, hi, i16, w, part);
                }
            } else {
                const unsigned* bsrc = xw ? (p ? h0b_ : h0a_)    // h0[t]
                                          : (p ? h1a_ : h1b_);   // h1[t-1]
                h_mfma(bsrc, A, kb, hi, i16, w, part);
            }
        }
        __syncthreads();   // SYNC_A: all partials for step t in LDS

        // ---- step 3: gates + cell update + h store (wave 0), then arrival ----
        if (active && tid < 64) {
            float gA[4], gB[4];
            #pragma unroll
            for (int g = 0; g < 4; ++g) {
                int mm = g * 4 + pr * 2;
                gA[g] = part[0 + ect][mm][ec]     + part[2 + ect][mm][ec]
                      + part[4 + ect][mm][ec]     + part[6 + ect][mm][ec]     + biasA[g];
                gB[g] = part[0 + ect][mm + 1][ec] + part[2 + ect][mm + 1][ec]
                      + part[4 + ect][mm + 1][ec] + part[6 + ect][mm + 1][ec] + biasB[g];
            }
            // gate order: i, f, g, o
            cA = sigf(gA[1]) * cA + sigf(gA[0]) * tanhf_fast(gA[2]);
            float hA = sigf(gA[3]) * tanhf_fast(cA);
            cB = sigf(gB[1]) * cB + sigf(gB[0]) * tanhf_fast(gB[2]);
            float hB = sigf(gB[3]) * tanhf_fast(cB);
            unsigned val = (unsigned)(unsigned short)f2bf(hA)
                         | ((unsigned)(unsigned short)f2bf(hB) << 16);
            unsigned* hout = l1 ? (p ? h1b_ : h1a_) : (p ? h0b_ : h0a_);
            st_a(hout + eb * (HID / 2) + s * 2 + pr, val);
        }
        if (tid == 0) {
            // drain wave-0's h stores to LLC, then post arrival (dense slot)
            asm volatile("s_waitcnt vmcnt(0)" ::: "memory");
            st_a(&slots[wg], (unsigned)(k + 1));
        }
        __syncthreads();   // SYNC_C: gate reads done; part[] free to overwrite

        // ---- step 5: L0 x-half for t+1 runs under the barrier wait ----
        if (!l1 && xw && active && (t + 1) < SEQ)
            l0_x_mfma(t + 1, tokens, emb, A, kb, hi, i16, w, part);

        // ---- step 6: poll my epoch copy (<=32 WGs per line) ----
        if (tid == NTHR - 1) {
            const unsigned target = (unsigned)(k + 1);
            while (!broken) {
                if (ld_a(myepoch) >= target) break;
                __builtin_amdgcn_s_sleep(1);
                if (++polls > POLL_CAP) broken = true;   // bailout: never hang
            }
        }
        __syncthreads();   // SYNC_D: all 256 workers arrived; fresh h visible
    }

    // ---- FC head: WG 0. h1 final (t=2047, parity 1) -> h1b ----
    if (wg == 0 && tid < 64) {
        const int b = tid >> 1, o = tid & 1;
        float acc = 0.f;
        for (int j2 = 0; j2 < HID / 2; ++j2) {
            unsigned u = ld_a(h1b_ + b * (HID / 2) + j2);
            acc += bf2f((unsigned short)(u & 0xFFFFu)) * fc_w[o * HID + 2 * j2]
                 + bf2f((unsigned short)(u >> 16))     * fc_w[o * HID + 2 * j2 + 1];
        }
        out[b * 2 + o] = sigf(acc + fc_b[o]);
    }
}

extern "C" void kernel_launch(void* const* d_in, const int* in_sizes, int n_in,
                              void* d_out, int out_size, void* d_ws, size_t ws_size,
                              hipStream_t stream)
{
    const int*   tokens = (const int*)d_in[0];
    const float* emb    = (const float*)d_in[1];
    const float* w_ih   = (const float*)d_in[2];
    const float* w_hh   = (const float*)d_in[3];
    const float* b_ih   = (const float*)d_in[4];
    const float* b_hh   = (const float*)d_in[5];
    const float* fc_w   = (const float*)d_in[6];
    const float* fc_b   = (const float*)d_in[7];

    unsigned* slots  = (unsigned*)((char*)d_ws + 256);    // 256 dense u32 (16 lines)
    unsigned* epochs = (unsigned*)((char*)d_ws + 4096);   // 8 copies, 128B apart
    unsigned* hbuf   = (unsigned*)((char*)d_ws + 65536);  // 4 x 8192 u32

    // zero slots + epochs + the 4 h buffers (h[-1] = 0); c lives in registers
    hipMemsetAsync(d_ws, 0, 65536 + (size_t)4 * NB * (HID / 2) * sizeof(unsigned), stream);

    lstm_persist<<<dim3(NWGW + 1), dim3(NTHR), 0, stream>>>(
        tokens, emb, w_ih, w_hh, b_ih, b_hh, fc_w, fc_b,
        (float*)d_out, slots, epochs, hbuf);
}

// Round 11
// 21573.865 us; speedup vs baseline: 1.7704x; 1.0621x over previous
//
#include <hip/hip_runtime.h>

#define SEQ   2048
#define EMBD  512
#define HID   512
#define NB    32
#define NWG   128   // one WG per 4-column slice, BOTH layers
#define NTHR  256
#define POLL_CAP 5000000

typedef __attribute__((ext_vector_type(8))) short bf16x8;
typedef __attribute__((ext_vector_type(4))) float f32x4;

__device__ __forceinline__ float sigf(float x) { return 1.0f / (1.0f + __expf(-x)); }
__device__ __forceinline__ float tanhf_fast(float x) {
    float e = __expf(2.0f * x);
    return (e - 1.0f) / (e + 1.0f);
}
__device__ __forceinline__ short f2bf(float f) {
    unsigned u = __float_as_uint(f);
    unsigned r = (u + 0x7FFFu + ((u >> 16) & 1u)) >> 16;
    return (short)r;
}
__device__ __forceinline__ float bf2f(unsigned short s) {
    return __uint_as_float(((unsigned)s) << 16);
}
__device__ __forceinline__ bf16x8 cvt8(float4 a, float4 b) {
    bf16x8 r;
    r[0] = f2bf(a.x); r[1] = f2bf(a.y); r[2] = f2bf(a.z); r[3] = f2bf(a.w);
    r[4] = f2bf(b.x); r[5] = f2bf(b.y); r[6] = f2bf(b.z); r[7] = f2bf(b.w);
    return r;
}

// Relaxed agent-scope atomics: proven prompt visibility (rounds 2-6, 9, 10).
__device__ __forceinline__ unsigned ld_a(const unsigned* p) {
    return __hip_atomic_load((unsigned*)p, __ATOMIC_RELAXED, __HIP_MEMORY_SCOPE_AGENT);
}
__device__ __forceinline__ void st_a(unsigned* p, unsigned v) {
    __hip_atomic_store(p, v, __ATOMIC_RELAXED, __HIP_MEMORY_SCOPE_AGENT);
}
__device__ __forceinline__ unsigned long long ld_a64(const unsigned long long* p) {
    return __hip_atomic_load((unsigned long long*)p, __ATOMIC_RELAXED, __HIP_MEMORY_SCOPE_AGENT);
}
// 16B fragment via two 8B atomic loads (16B-aligned source)
__device__ __forceinline__ bf16x8 ld_h8(const unsigned* p) {
    union { unsigned long long u[2]; bf16x8 v; } x;
    x.u[0] = ld_a64((const unsigned long long*)p);
    x.u[1] = ld_a64((const unsigned long long*)(p + 2));
    return x.v;
}

// Full-K (512) MFMA half-GEMM on h-state (u32-packed bf16 pairs) -> LDS partials
__device__ __forceinline__ void h_mfma16(
    const unsigned* __restrict__ bsrc, const bf16x8* A,
    int hi, int i16, float (*out)[16][16])
{
    f32x4 acc0 = {0.f, 0.f, 0.f, 0.f};
    f32x4 acc1 = {0.f, 0.f, 0.f, 0.f};
    const unsigned* pb0 = bsrc + (size_t)i16 * 256;
    const unsigned* pb1 = bsrc + (size_t)(16 + i16) * 256;
    #pragma unroll
    for (int kt = 0; kt < 16; ++kt) {
        int ko = kt * 16 + hi * 4;
        bf16x8 B0 = ld_h8(pb0 + ko);
        bf16x8 B1 = ld_h8(pb1 + ko);
        acc0 = __builtin_amdgcn_mfma_f32_16x16x32_bf16(A[kt], B0, acc0, 0, 0, 0);
        acc1 = __builtin_amdgcn_mfma_f32_16x16x32_bf16(A[kt], B1, acc1, 0, 0, 0);
    }
    #pragma unroll
    for (int r = 0; r < 4; ++r) {
        out[0][hi * 4 + r][i16] = acc0[r];
        out[1][hi * 4 + r][i16] = acc1[r];
    }
}

// Full-K (512) x-part (embedding gather) for step tt -> LDS partials
__device__ __forceinline__ void x_mfma16(
    int tt, const int* __restrict__ tokens, const float* __restrict__ emb,
    const bf16x8* A, int hi, int i16, float (*out)[16][16])
{
    f32x4 acc0 = {0.f, 0.f, 0.f, 0.f};
    f32x4 acc1 = {0.f, 0.f, 0.f, 0.f};
    const size_t r0 = (size_t)tokens[i16 * SEQ + tt] * EMBD;
    const size_t r1 = (size_t)tokens[(16 + i16) * SEQ + tt] * EMBD;
    #pragma unroll
    for (int kt = 0; kt < 16; ++kt) {
        int koff = kt * 32 + hi * 8;
        float4 xa0 = *(const float4*)(emb + r0 + koff);
        float4 xb0 = *(const float4*)(emb + r0 + koff + 4);
        float4 xa1 = *(const float4*)(emb + r1 + koff);
        float4 xb1 = *(const float4*)(emb + r1 + koff + 4);
        bf16x8 B0 = cvt8(xa0, xb0);
        bf16x8 B1 = cvt8(xa1, xb1);
        acc0 = __builtin_amdgcn_mfma_f32_16x16x32_bf16(A[kt], B0, acc0, 0, 0, 0);
        acc1 = __builtin_amdgcn_mfma_f32_16x16x32_bf16(A[kt], B1, acc1, 0, 0, 0);
    }
    #pragma unroll
    for (int r = 0; r < 4; ++r) {
        out[0][hi * 4 + r][i16] = acc0[r];
        out[1][hi * 4 + r][i16] = acc1[r];
    }
}

// Persistent kernel, 128 WGs, both layers per WG.
// Waves: w0 = W_ih0 (x-part, pipelined under the wait), w1 = W_hh0,
//        w2 = W_ih1 (input = h0) + L0 cell update, w3 = W_hh1 + L1 cell update.
// WG0's w1 is the inline barrier master (sweeps 128 dense slots -> epoch).
__global__ __launch_bounds__(NTHR, 1) void lstm_persist(
    const int*   __restrict__ tokens, const float* __restrict__ emb,
    const float* __restrict__ w_ih,   const float* __restrict__ w_hh,
    const float* __restrict__ b_ih,   const float* __restrict__ b_hh,
    const float* __restrict__ fc_w,   const float* __restrict__ fc_b,
    float* __restrict__ out,
    unsigned* __restrict__ epoch, unsigned* __restrict__ slots,
    unsigned* __restrict__ hbuf)
{
    __shared__ float part[4][2][16][16];   // [wave][ct][m][c]

    const int tid  = threadIdx.x;
    const int s    = blockIdx.x;          // slice: cols s*4 .. s*4+3 (both layers)
    const int w    = tid >> 6;
    const int lane = tid & 63;
    const int i16  = lane & 15;
    const int hi   = lane >> 4;
    const int lay   = w >> 1;             // wave's weight layer
    const bool xpart = !(w & 1);          // w0,w2: ih ; w1,w3: hh

    unsigned* const hb[2][2] = {                    // [which][parity]
        { hbuf,              hbuf +  8192 },        // h0: a(par0), b(par1)
        { hbuf + 16384,      hbuf + 24576 } };      // h1

    // ---- A fragments: full K=512 of this wave's matrix, resident (64 VGPR) ----
    const int m    = i16;
    const int gg_  = m >> 2, jj_ = m & 3;
    const int rowg = gg_ * 512 + s * 4 + jj_;
    const float* wbase = (xpart ? w_ih : w_hh) + ((size_t)lay * 2048 + rowg) * 512;
    bf16x8 A[16];
    #pragma unroll
    for (int kt = 0; kt < 16; ++kt) {
        int koff = kt * 32 + hi * 8;
        A[kt] = cvt8(*(const float4*)(wbase + koff), *(const float4*)(wbase + koff + 4));
    }

    // ---- cell roles: w2 -> L0 state, w3 -> L1 state ----
    const int eb = lane & 31, pr = lane >> 5;
    const int ect = eb >> 4, ec = eb & 15;
    float cA = 0.f, cB = 0.f;
    float biasA[4] = {0,0,0,0}, biasB[4] = {0,0,0,0};
    if (w >= 2) {
        const int cl = w - 2;   // cell layer
        #pragma unroll
        for (int g = 0; g < 4; ++g) {
            int rg = g * 512 + s * 4 + pr * 2;
            biasA[g] = b_ih[cl * 2048 + rg]     + b_hh[cl * 2048 + rg];
            biasB[g] = b_ih[cl * 2048 + rg + 1] + b_hh[cl * 2048 + rg + 1];
        }
    }

    bool broken = false;
    int polls = 0;

    // ---- prologue: x-part for t=0 ----
    if (w == 0) x_mfma16(0, tokens, emb, A, hi, i16, part[0]);

    for (int k = 0; k <= SEQ; ++k) {
        const bool l0act = (k < SEQ);       // L0 computes h0[k]
        const bool l1act = (k >= 1);        // L1 computes h1[k-1]

        // ---- step 1: MFMA on inputs confirmed at the previous barrier ----
        if (w == 1 && l0act) h_mfma16(hb[0][(k - 1) & 1], A, hi, i16, part[1]); // W_hh0 . h0[k-1]
        if (w == 2 && l1act) h_mfma16(hb[0][(k - 1) & 1], A, hi, i16, part[2]); // W_ih1 . h0[k-1]
        if (w == 3 && l1act) h_mfma16(hb[1][k & 1],       A, hi, i16, part[3]); // W_hh1 . h1[k-2]
        __syncthreads();   // SYNC_A: all partials in LDS

        // ---- step 2: parallel cell updates + h stores + per-wave drains ----
        if (w == 2 && l0act) {
            float gA[4], gB[4];
            #pragma unroll
            for (int g = 0; g < 4; ++g) {
                int mm = g * 4 + pr * 2;
                gA[g] = part[0][ect][mm][ec]     + part[1][ect][mm][ec]     + biasA[g];
                gB[g] = part[0][ect][mm + 1][ec] + part[1][ect][mm + 1][ec] + biasB[g];
            }
            cA = sigf(gA[1]) * cA + sigf(gA[0]) * tanhf_fast(gA[2]);
            float hA = sigf(gA[3]) * tanhf_fast(cA);
            cB = sigf(gB[1]) * cB + sigf(gB[0]) * tanhf_fast(gB[2]);
            float hB = sigf(gB[3]) * tanhf_fast(cB);
            unsigned val = (unsigned)(unsigned short)f2bf(hA)
                         | ((unsigned)(unsigned short)f2bf(hB) << 16);
            st_a(hb[0][k & 1] + eb * 256 + s * 2 + pr, val);
            asm volatile("s_waitcnt vmcnt(0)" ::: "memory");
        }
        if (w == 3 && l1act) {
            float gA[4], gB[4];
            #pragma unroll
            for (int g = 0; g < 4; ++g) {
                int mm = g * 4 + pr * 2;
                gA[g] = part[2][ect][mm][ec]     + part[3][ect][mm][ec]     + biasA[g];
                gB[g] = part[2][ect][mm + 1][ec] + part[3][ect][mm + 1][ec] + biasB[g];
            }
            cA = sigf(gA[1]) * cA + sigf(gA[0]) * tanhf_fast(gA[2]);
            float hA = sigf(gA[3]) * tanhf_fast(cA);
            cB = sigf(gB[1]) * cB + sigf(gB[0]) * tanhf_fast(gB[2]);
            float hB = sigf(gB[3]) * tanhf_fast(cB);
            unsigned val = (unsigned)(unsigned short)f2bf(hA)
                         | ((unsigned)(unsigned short)f2bf(hB) << 16);
            st_a(hb[1][(k - 1) & 1] + eb * 256 + s * 2 + pr, val);
            asm volatile("s_waitcnt vmcnt(0)" ::: "memory");
        }
        __syncthreads();   // SYNC_B: both h slices at the coherence point

        // ---- step 3: arrival + pipelined x-part + master sweep + poll ----
        if (tid == 0) st_a(&slots[s], (unsigned)(k + 1));

        if (w == 0 && (k + 1) < SEQ)
            x_mfma16(k + 1, tokens, emb, A, hi, i16, part[0]);   // under the wait

        if (s == 0 && w == 1) {
            const unsigned target = (unsigned)(k + 1);
            for (;;) {
                if (broken) break;
                unsigned v0 = ld_a(&slots[lane]);
                unsigned v1 = ld_a(&slots[lane + 64]);
                if (__all((v0 >= target) & (v1 >= target))) break;
                if (++polls > POLL_CAP) broken = true;   // bailout: never hang
            }
            if (lane == 0) st_a(epoch, broken ? (unsigned)(SEQ + 2) : (unsigned)(k + 1));
        }
        if (tid == NTHR - 1) {
            const unsigned target = (unsigned)(k + 1);
            while (!broken) {
                if (ld_a(epoch) >= target) break;
                __builtin_amdgcn_s_sleep(1);
                if (++polls > POLL_CAP) broken = true;   // bailout: never hang
            }
        }
        __syncthreads();   // SYNC_D: all 128 WGs arrived; fresh h visible
    }

    // ---- FC head: WG 0. h1 final (t=2047, parity 1) -> hb[1][1] ----
    if (s == 0 && tid < 64) {
        const int b = tid >> 1, o = tid & 1;
        const unsigned* hf = hb[1][1];
        float acc = 0.f;
        for (int j2 = 0; j2 < 256; ++j2) {
            unsigned u = ld_a(hf + b * 256 + j2);
            acc += bf2f((unsigned short)(u & 0xFFFFu)) * fc_w[o * HID + 2 * j2]
                 + bf2f((unsigned short)(u >> 16))     * fc_w[o * HID + 2 * j2 + 1];
        }
        out[b * 2 + o] = sigf(acc + fc_b[o]);
    }
}

extern "C" void kernel_launch(void* const* d_in, const int* in_sizes, int n_in,
                              void* d_out, int out_size, void* d_ws, size_t ws_size,
                              hipStream_t stream)
{
    const int*   tokens = (const int*)d_in[0];
    const float* emb    = (const float*)d_in[1];
    const float* w_ih   = (const float*)d_in[2];
    const float* w_hh   = (const float*)d_in[3];
    const float* b_ih   = (const float*)d_in[4];
    const float* b_hh   = (const float*)d_in[5];
    const float* fc_w   = (const float*)d_in[6];
    const float* fc_b   = (const float*)d_in[7];

    unsigned* epoch = (unsigned*)d_ws;                     // own line
    unsigned* slots = (unsigned*)((char*)d_ws + 256);      // 128 dense u32 (8 lines)
    unsigned* hbuf  = (unsigned*)((char*)d_ws + 65536);    // 4 x 8192 u32

    // zero epoch + slots + the 4 h buffers (h[-1] = 0); c lives in registers
    hipMemsetAsync(d_ws, 0, 65536 + (size_t)4 * NB * (HID / 2) * sizeof(unsigned), stream);

    lstm_persist<<<dim3(NWG), dim3(NTHR), 0, stream>>>(
        tokens, emb, w_ih, w_hh, b_ih, b_hh, fc_w, fc_b,
        (float*)d_out, epoch, slots, hbuf);
}

// Round 12
// 12165.991 us; speedup vs baseline: 3.1395x; 1.7733x over previous
//
#include <hip/hip_runtime.h>

#define SEQ   2048
#define EMBD  512
#define HID   512
#define NB    32
#define NSL   128   // WGs per layer
#define NWG   256
#define NTHR  256

typedef __attribute__((ext_vector_type(8))) short bf16x8;
typedef __attribute__((ext_vector_type(4))) float f32x4;

__device__ __forceinline__ float sigf(float x) { return 1.0f / (1.0f + __expf(-x)); }
__device__ __forceinline__ float tanhf_fast(float x) {
    float e = __expf(2.0f * x);
    return (e - 1.0f) / (e + 1.0f);
}
__device__ __forceinline__ short f2bf(float f) {
    unsigned u = __float_as_uint(f);
    unsigned r = (u + 0x7FFFu + ((u >> 16) & 1u)) >> 16;
    return (short)r;
}
__device__ __forceinline__ float bf2f(unsigned short s) {
    return __uint_as_float(((unsigned)s) << 16);
}
__device__ __forceinline__ unsigned pack2(float a, float b) {
    return (unsigned)(unsigned short)f2bf(a) | ((unsigned)(unsigned short)f2bf(b) << 16);
}
__device__ __forceinline__ bf16x8 cvt8(float4 a, float4 b) {
    bf16x8 r;
    r[0] = f2bf(a.x); r[1] = f2bf(a.y); r[2] = f2bf(a.z); r[3] = f2bf(a.w);
    r[4] = f2bf(b.x); r[5] = f2bf(b.y); r[6] = f2bf(b.z); r[7] = f2bf(b.w);
    return r;
}

// ---- node 0: repack f32 weights -> bf16 MFMA A-fragments (layout matches
// lstm_step's consumption exactly; indexing identical to R4's in-register load)
__global__ __launch_bounds__(NTHR, 1) void repack_w(
    const float* __restrict__ w_ih, const float* __restrict__ w_hh,
    bf16x8* __restrict__ wsW)
{
    const int wg  = blockIdx.x, tid = threadIdx.x;
    const bool l1 = (wg >= NSL);
    const int s   = l1 ? (wg - NSL) : wg;
    const int layer = l1 ? 1 : 0;
    const int w = tid >> 6, lane = tid & 63, i16 = lane & 15, hi = lane >> 4;
    const int kb = (w & 1) * 256;
    const bool xw = (w < 2);
    const int gg_ = i16 >> 2, jj_ = i16 & 3;
    const int rowg = gg_ * 512 + s * 4 + jj_;
    const float* wbase = xw ? (w_ih + ((size_t)layer * 2048 + rowg) * 512)
                            : (w_hh + ((size_t)layer * 2048 + rowg) * 512);
    #pragma unroll
    for (int q = 0; q < 8; ++q) {
        int koff = kb + q * 32 + hi * 8;
        wsW[(((size_t)wg * 4 + w) * 8 + q) * 64 + lane] =
            cvt8(*(const float4*)(wbase + koff), *(const float4*)(wbase + koff + 4));
    }
}

// ---- one timestep node: WGs [0,128) = L0 step k, WGs [128,256) = L1 step k-1.
// Inter-node ordering + cache coherence come from the graph edge (stream order);
// NO atomics, NO polls, NO drains. Math/layout identical to the 4x-validated R4.
__global__ __launch_bounds__(NTHR, 1) void lstm_step(
    int k,
    const int*   __restrict__ tokens, const float* __restrict__ emb,
    const bf16x8* __restrict__ wsW,
    const float* __restrict__ b_ih,   const float* __restrict__ b_hh,
    unsigned* __restrict__ hbuf, float* __restrict__ cbuf)
{
    __shared__ float part[8][16][16];   // [w*2+ct][m][c]

    const int wg  = blockIdx.x, tid = threadIdx.x;
    const bool l1 = (wg >= NSL);
    const int s   = l1 ? (wg - NSL) : wg;
    const int layer = l1 ? 1 : 0;
    const int t = l1 ? (k - 1) : k;
    if (t < 0 || t >= SEQ) return;      // uniform per WG
    const int p = t & 1;

    const int w = tid >> 6, lane = tid & 63, i16 = lane & 15, hi = lane >> 4;
    const int kb = (w & 1) * 256;
    const bool xw = (w < 2);

    unsigned* const h0a_ = hbuf;
    unsigned* const h0b_ = hbuf + 8192;
    unsigned* const h1a_ = hbuf + 16384;
    unsigned* const h1b_ = hbuf + 24576;

    // A fragments: coalesced 16B loads from the repacked bf16 buffer (L2-warm)
    bf16x8 A[8];
    const bf16x8* wp = wsW + (((size_t)wg * 4 + w) * 8) * 64 + lane;
    #pragma unroll
    for (int q = 0; q < 8; ++q) A[q] = wp[q * 64];

    // B source selection (same pipelining as R4):
    //  L0: xw -> embedding gather of x_t ; else h0[t-1]
    //  L1: xw -> h0[t] (written by L0 in the PREVIOUS node) ; else h1[t-1]
    const unsigned* bsrc;
    if (!l1) bsrc = xw ? (const unsigned*)nullptr : (p ? h0a_ : h0b_);
    else     bsrc = xw ? (p ? h0b_ : h0a_) : (p ? h1a_ : h1b_);

    f32x4 acc0 = {0.f, 0.f, 0.f, 0.f};
    f32x4 acc1 = {0.f, 0.f, 0.f, 0.f};

    if (bsrc == nullptr) {
        const int b0 = i16, b1 = 16 + i16;
        const size_t r0 = (size_t)tokens[b0 * SEQ + t] * EMBD;
        const size_t r1 = (size_t)tokens[b1 * SEQ + t] * EMBD;
        #pragma unroll
        for (int q = 0; q < 8; ++q) {
            int koff = kb + q * 32 + hi * 8;
            float4 xa0 = *(const float4*)(emb + r0 + koff);
            float4 xb0 = *(const float4*)(emb + r0 + koff + 4);
            float4 xa1 = *(const float4*)(emb + r1 + koff);
            float4 xb1 = *(const float4*)(emb + r1 + koff + 4);
            bf16x8 B0 = cvt8(xa0, xb0);
            bf16x8 B1 = cvt8(xa1, xb1);
            acc0 = __builtin_amdgcn_mfma_f32_16x16x32_bf16(A[q], B0, acc0, 0, 0, 0);
            acc1 = __builtin_amdgcn_mfma_f32_16x16x32_bf16(A[q], B1, acc1, 0, 0, 0);
        }
    } else {
        const unsigned* pb0 = bsrc + (size_t)i16 * 256;
        const unsigned* pb1 = bsrc + (size_t)(16 + i16) * 256;
        const int kb2 = kb / 2;
        #pragma unroll
        for (int q = 0; q < 8; ++q) {
            int ko2 = kb2 + q * 16 + hi * 4;
            bf16x8 B0 = *(const bf16x8*)(pb0 + ko2);   // plain loads: graph edge
            bf16x8 B1 = *(const bf16x8*)(pb1 + ko2);   // guarantees freshness
            acc0 = __builtin_amdgcn_mfma_f32_16x16x32_bf16(A[q], B0, acc0, 0, 0, 0);
            acc1 = __builtin_amdgcn_mfma_f32_16x16x32_bf16(A[q], B1, acc1, 0, 0, 0);
        }
    }

    // C mapping (verified): col = lane&15, row = (lane>>4)*4 + reg
    #pragma unroll
    for (int r = 0; r < 4; ++r) {
        part[w * 2 + 0][hi * 4 + r][i16] = acc0[r];
        part[w * 2 + 1][hi * 4 + r][i16] = acc1[r];
    }
    __syncthreads();

    // cell update: threads 0..63 own (pr, eb), 2 hidden cols each
    if (tid < 64) {
        const int eb = tid & 31, pr = tid >> 5;
        const int ect = eb >> 4, ec = eb & 15;
        float gA[4], gB[4];
        #pragma unroll
        for (int g = 0; g < 4; ++g) {
            const int mm = g * 4 + pr * 2;
            const int rg = g * 512 + s * 4 + pr * 2;
            const float bA = b_ih[layer * 2048 + rg]     + b_hh[layer * 2048 + rg];
            const float bB = b_ih[layer * 2048 + rg + 1] + b_hh[layer * 2048 + rg + 1];
            gA[g] = part[0 + ect][mm][ec]     + part[2 + ect][mm][ec]
                  + part[4 + ect][mm][ec]     + part[6 + ect][mm][ec]     + bA;
            gB[g] = part[0 + ect][mm + 1][ec] + part[2 + ect][mm + 1][ec]
                  + part[4 + ect][mm + 1][ec] + part[6 + ect][mm + 1][ec] + bB;
        }
        float* cp = cbuf + (layer ? 16384 : 0) + eb * 512 + s * 4 + pr * 2;
        float2 c2 = *(float2*)cp;
        // gate order: i, f, g, o
        const float cA = sigf(gA[1]) * c2.x + sigf(gA[0]) * tanhf_fast(gA[2]);
        const float hA = sigf(gA[3]) * tanhf_fast(cA);
        const float cB = sigf(gB[1]) * c2.y + sigf(gB[0]) * tanhf_fast(gB[2]);
        const float hB = sigf(gB[3]) * tanhf_fast(cB);
        *(float2*)cp = make_float2(cA, cB);
        unsigned* hout = l1 ? (p ? h1b_ : h1a_) : (p ? h0b_ : h0a_);
        hout[eb * 256 + s * 2 + pr] = pack2(hA, hB);
    }
}

__global__ void fc_head(const unsigned* __restrict__ h1fin,
                        const float* __restrict__ fc_w,
                        const float* __restrict__ fc_b,
                        float* __restrict__ out)
{
    const int tid = threadIdx.x;
    if (tid >= 64) return;
    const int b = tid >> 1, o = tid & 1;
    float acc = 0.f;
    for (int j2 = 0; j2 < 256; ++j2) {
        unsigned u = h1fin[b * 256 + j2];
        acc += bf2f((unsigned short)(u & 0xFFFFu)) * fc_w[o * HID + 2 * j2]
             + bf2f((unsigned short)(u >> 16))     * fc_w[o * HID + 2 * j2 + 1];
    }
    out[b * 2 + o] = sigf(acc + fc_b[o]);
}

extern "C" void kernel_launch(void* const* d_in, const int* in_sizes, int n_in,
                              void* d_out, int out_size, void* d_ws, size_t ws_size,
                              hipStream_t stream)
{
    const int*   tokens = (const int*)d_in[0];
    const float* emb    = (const float*)d_in[1];
    const float* w_ih   = (const float*)d_in[2];
    const float* w_hh   = (const float*)d_in[3];
    const float* b_ih   = (const float*)d_in[4];
    const float* b_hh   = (const float*)d_in[5];
    const float* fc_w   = (const float*)d_in[6];
    const float* fc_b   = (const float*)d_in[7];

    unsigned* hbuf = (unsigned*)((char*)d_ws + 65536);          // 4 x 32 KB h buffers
    float*    cbuf = (float*)((char*)d_ws + 65536 + 131072);    // 2 x 64 KB c state
    bf16x8*   wsW  = (bf16x8*)((char*)d_ws + 65536 + 262144);   // 2 MB bf16 fragments

    // zero h (h[-1]=0) and c (c[-1]=0); weights repacked fresh each call
    hipMemsetAsync((char*)d_ws + 65536, 0, 262144, stream);
    repack_w<<<dim3(NWG), dim3(NTHR), 0, stream>>>(w_ih, w_hh, wsW);

    for (int k = 0; k <= SEQ; ++k)
        lstm_step<<<dim3(NWG), dim3(NTHR), 0, stream>>>(
            k, tokens, emb, wsW, b_ih, b_hh, hbuf, cbuf);

    // h1 final: t=2047, parity 1 -> h1b (hbuf + 24576)
    fc_head<<<dim3(1), dim3(64), 0, stream>>>(hbuf + 24576, fc_w, fc_b, (float*)d_out);
}

// Round 14
// 10656.541 us; speedup vs baseline: 3.5842x; 1.1416x over previous
//
#include <hip/hip_runtime.h>

#define SEQ   2048
#define EMBD  512
#define HID   512
#define NSL   128   // role-slices per layer
#define NTHR  256

typedef __attribute__((ext_vector_type(8))) short bf16x8;
typedef __attribute__((ext_vector_type(4))) float f32x4;

__device__ __forceinline__ float sigf(float x) { return 1.0f / (1.0f + __expf(-x)); }
__device__ __forceinline__ float tanhf_fast(float x) {
    float e = __expf(2.0f * x);
    return (e - 1.0f) / (e + 1.0f);
}
__device__ __forceinline__ short f2bf(float f) {
    unsigned u = __float_as_uint(f);
    unsigned r = (u + 0x7FFFu + ((u >> 16) & 1u)) >> 16;
    return (short)r;
}
__device__ __forceinline__ float bf2f(unsigned short s) {
    return __uint_as_float(((unsigned)s) << 16);
}
__device__ __forceinline__ bf16x8 cvt8(float4 a, float4 b) {
    bf16x8 r;
    r[0] = f2bf(a.x); r[1] = f2bf(a.y); r[2] = f2bf(a.z); r[3] = f2bf(a.w);
    r[4] = f2bf(b.x); r[5] = f2bf(b.y); r[6] = f2bf(b.z); r[7] = f2bf(b.w);
    return r;
}

// ---- prep: repack f32 weights -> bf16 MFMA A-fragments (R12-identical; 8 MB) ----
__global__ __launch_bounds__(NTHR, 1) void repack_w(
    const float* __restrict__ w_ih, const float* __restrict__ w_hh,
    bf16x8* __restrict__ wsW)
{
    const int role = blockIdx.x, tid = threadIdx.x;
    const bool l1 = (role >= NSL);
    const int s   = l1 ? (role - NSL) : role;
    const int layer = l1 ? 1 : 0;
    const int w = tid >> 6, lane = tid & 63, i16 = lane & 15, hi = lane >> 4;
    const int kb = (w & 1) * 256;
    const bool xw = (w < 2);
    const int gg_ = i16 >> 2, jj_ = i16 & 3;
    const int rowg = gg_ * 512 + s * 4 + jj_;
    const float* wbase = xw ? (w_ih + ((size_t)layer * 2048 + rowg) * 512)
                            : (w_hh + ((size_t)layer * 2048 + rowg) * 512);
    #pragma unroll
    for (int q = 0; q < 8; ++q) {
        int koff = kb + q * 32 + hi * 8;
        wsW[(((size_t)role * 4 + w) * 8 + q) * 64 + lane] =
            cvt8(*(const float4*)(wbase + koff), *(const float4*)(wbase + koff + 4));
    }
}

// ---- prep: transpose tokens [B][T] -> [T][B] (one coalesced line per step) ----
__global__ void tok_t(const int* __restrict__ tokens, int* __restrict__ tokT)
{
    const int idx = blockIdx.x * NTHR + threadIdx.x;   // 65536 total
    const int t = idx >> 5, b = idx & 31;
    tokT[idx] = tokens[b * SEQ + t];
}

// ---- prep: pre-add biases ----
__global__ void bias_prep(const float* __restrict__ b_ih, const float* __restrict__ b_hh,
                          float* __restrict__ wsB)
{
    const int idx = blockIdx.x * NTHR + threadIdx.x;   // 4096 total
    wsB[idx] = b_ih[idx] + b_hh[idx];
}

// ---- one timestep node, batch-split grid of 512 WGs:
// wg>>1 = role (0-127: L0 step k; 128-255: L1 step k-1), wg&1 = batch half.
// Each WG: 4 waves x 8 MFMAs on a 16-batch block. Inter-node ordering +
// coherence from the graph edge; no atomics, no polls, no drains.
__global__ __launch_bounds__(NTHR, 1) void lstm_step(
    int k,
    const int*   __restrict__ tokT, const float* __restrict__ emb,
    const bf16x8* __restrict__ wsW, const float* __restrict__ wsB,
    unsigned short* __restrict__ h16, float* __restrict__ cbuf)
{
    __shared__ float part[4][16][16];   // [wave(K-partial)][m][batch-in-block]

    const int wg  = blockIdx.x, tid = threadIdx.x;
    const int role = wg >> 1, bo = (wg & 1) << 4;
    const bool l1 = (role >= NSL);
    const int s   = l1 ? (role - NSL) : role;
    const int layer = l1 ? 1 : 0;
    const int t = l1 ? (k - 1) : k;
    if (t < 0 || t >= SEQ) return;      // uniform per WG
    const int p = t & 1;

    const int w = tid >> 6, lane = tid & 63, i16 = lane & 15, hi = lane >> 4;
    const int kb = (w & 1) * 256;
    const bool xw = (w < 2);

    unsigned short* const h0a_ = h16;
    unsigned short* const h0b_ = h16 + 16384;
    unsigned short* const h1a_ = h16 + 32768;
    unsigned short* const h1b_ = h16 + 49152;

    // A fragments: coalesced 16B loads, L2-resident across nodes
    bf16x8 A[8];
    const bf16x8* wp = wsW + (((size_t)role * 4 + w) * 8) * 64 + lane;
    #pragma unroll
    for (int q = 0; q < 8; ++q) A[q] = wp[q * 64];

    // B source (R12-proven pipelining):
    //  L0: xw -> x_t gather ; else h0[t-1].  L1: xw -> h0[t] ; else h1[t-1].
    const unsigned short* bsrc;
    if (!l1) bsrc = xw ? (const unsigned short*)nullptr : (p ? h0a_ : h0b_);
    else     bsrc = xw ? (p ? h0b_ : h0a_) : (p ? h1a_ : h1b_);

    f32x4 acc = {0.f, 0.f, 0.f, 0.f};

    if (bsrc == nullptr) {
        const size_t r0 = (size_t)tokT[t * 32 + bo + i16] * EMBD;   // 1 coalesced line
        #pragma unroll
        for (int q = 0; q < 8; ++q) {
            int koff = kb + q * 32 + hi * 8;
            float4 xa = *(const float4*)(emb + r0 + koff);
            float4 xb = *(const float4*)(emb + r0 + koff + 4);
            acc = __builtin_amdgcn_mfma_f32_16x16x32_bf16(A[q], cvt8(xa, xb), acc, 0, 0, 0);
        }
    } else {
        const unsigned short* pb = bsrc + (size_t)(bo + i16) * 512 + kb;
        #pragma unroll
        for (int q = 0; q < 8; ++q) {
            bf16x8 B = *(const bf16x8*)(pb + q * 32 + hi * 8);   // plain loads: graph
            acc = __builtin_amdgcn_mfma_f32_16x16x32_bf16(A[q], B, acc, 0, 0, 0);
        }
    }

    // C mapping (verified): col = lane&15 (batch-in-block), row = hi*4 + reg
    #pragma unroll
    for (int r = 0; r < 4; ++r) part[w][hi * 4 + r][i16] = acc[r];
    __syncthreads();

    // cell update: 64 threads, one (col, batch) cell each
    if (tid < 64) {
        const int jj = tid >> 4, bb = tid & 15, eb = bo + bb;
        float g4[4];
        #pragma unroll
        for (int g = 0; g < 4; ++g)
            g4[g] = part[0][g * 4 + jj][bb] + part[1][g * 4 + jj][bb]
                  + part[2][g * 4 + jj][bb] + part[3][g * 4 + jj][bb]
                  + wsB[layer * 2048 + g * 512 + s * 4 + jj];
        float* cp = cbuf + layer * 16384 + eb * 512 + s * 4 + jj;
        float c = *cp;
        // gate order: i, f, g, o
        c = sigf(g4[1]) * c + sigf(g4[0]) * tanhf_fast(g4[2]);
        const float h = sigf(g4[3]) * tanhf_fast(c);
        *cp = c;
        unsigned short* hout = l1 ? (p ? h1b_ : h1a_) : (p ? h0b_ : h0a_);
        hout[eb * 512 + s * 4 + jj] = (unsigned short)f2bf(h);
    }
}

__global__ void fc_head(const unsigned short* __restrict__ h1fin,
                        const float* __restrict__ fc_w,
                        const float* __restrict__ fc_b,
                        float* __restrict__ out)
{
    const int tid = threadIdx.x;
    if (tid >= 64) return;
    const int b = tid >> 1, o = tid & 1;
    float acc = 0.f;
    for (int j = 0; j < HID; ++j)
        acc += bf2f(h1fin[b * 512 + j]) * fc_w[o * HID + j];
    out[b * 2 + o] = sigf(acc + fc_b[o]);
}

extern "C" void kernel_launch(void* const* d_in, const int* in_sizes, int n_in,
                              void* d_out, int out_size, void* d_ws, size_t ws_size,
                              hipStream_t stream)
{
    const int*   tokens = (const int*)d_in[0];
    const float* emb    = (const float*)d_in[1];
    const float* w_ih   = (const float*)d_in[2];
    const float* w_hh   = (const float*)d_in[3];
    const float* b_ih   = (const float*)d_in[4];
    const float* b_hh   = (const float*)d_in[5];
    const float* fc_w   = (const float*)d_in[6];
    const float* fc_b   = (const float*)d_in[7];

    // ---- workspace layout (disjoint, verified by arithmetic):
    //   +0        wsB   16 KB   (pre-added biases)
    //   +65536    h16   128 KB  (4 x 32 KB h buffers, bf16 [b][j])
    //   +196608   cbuf  128 KB  (2 x 64 KB f32 c state)
    //   +327680   tokT  256 KB  ([T][32] token table)
    //   +589824   wsW   8 MB    (ALL bf16 weight fragments: 256 roles x 32 KB)
    //   total ~8.98 MB (R12's working footprint was 8.7 MB)
    float*          wsB  = (float*)d_ws;
    unsigned short* h16  = (unsigned short*)((char*)d_ws + 65536);
    float*          cbuf = (float*)((char*)d_ws + 196608);
    int*            tokT = (int*)((char*)d_ws + 327680);
    bf16x8*         wsW  = (bf16x8*)((char*)d_ws + 589824);

    // zero h (h[-1]=0) and c
    hipMemsetAsync((char*)d_ws + 65536, 0, 262144, stream);
    tok_t    <<<dim3(256), dim3(NTHR), 0, stream>>>(tokens, tokT);
    bias_prep<<<dim3(16),  dim3(NTHR), 0, stream>>>(b_ih, b_hh, wsB);
    repack_w <<<dim3(256), dim3(NTHR), 0, stream>>>(w_ih, w_hh, wsW);

    for (int k = 0; k <= SEQ; ++k)
        lstm_step<<<dim3(512), dim3(NTHR), 0, stream>>>(
            k, tokT, emb, wsW, wsB, h16, cbuf);

    // h1 final: t=2047, parity 1 -> h1b
    fc_head<<<dim3(1), dim3(64), 0, stream>>>(h16 + 49152, fc_w, fc_b, (float*)d_out);
}